// Round 9
// baseline (826.241 us; speedup 1.0000x reference)
//
#include <hip/hip_runtime.h>
#include <hip/hip_bf16.h>
#include <stdint.h>

// TreeLSTM on MI355X. H=D=128, 5H=640, N_LEAVES=2^18, 18 internal levels.
// v3: separate leaf cast (bf16 A everywhere), LDS weight panel per block,
// grid-stride rows, fused tail kernel (10 smallest levels, grid barrier).

#define H5 640
#define HH 128
#define NLEAF 262144

typedef __attribute__((ext_vector_type(4))) float f32x4;
typedef __attribute__((ext_vector_type(8))) short bf16x8;
typedef __attribute__((ext_vector_type(4))) unsigned int u32x4;

static __device__ __forceinline__ unsigned int f2bf(float f) {
  union { float f; unsigned int i; } v; v.f = f;
  unsigned int r = v.i + 0x7FFF + ((v.i >> 16) & 1);  // RNE
  return r >> 16;
}

static __device__ __forceinline__ float sigf(float x) {
  return 1.0f / (1.0f + __expf(-x));
}
static __device__ __forceinline__ float tanh_fast(float x) {
  float t = __expf(2.0f * x);
  return (t - 1.0f) / (t + 1.0f);
}

// ---------------------------------------------------------------------------
// Pack a [K,640] f32 weight (rows k<split from srcA, else srcB) into MFMA
// B-fragment layout: frag (nf,kf): lane l holds B[kf*32+(l>>4)*8+e][nf*16+(l&15)],
// e=0..7. Element offset = ((nf*KT + kf)*64 + lane)*8.  (validated r1/r4)
__global__ void pack_weights(const float* __restrict__ srcA,
                             const float* __restrict__ srcB,
                             int split, int KT, unsigned short* __restrict__ dst) {
  int t = blockIdx.x * blockDim.x + threadIdx.x;
  int total = 40 * KT * 64;
  if (t >= total) return;
  int lane = t & 63;
  int kf = (t >> 6) % KT;
  int nf = (t >> 6) / KT;
  int col = nf * 16 + (lane & 15);
  int k0 = kf * 32 + (lane >> 4) * 8;
  unsigned int w[4];
#pragma unroll
  for (int p = 0; p < 4; ++p) {
    int ka = k0 + 2 * p, kb = k0 + 2 * p + 1;
    float fa = (ka < split) ? srcA[(size_t)ka * H5 + col] : srcB[(size_t)(ka - split) * H5 + col];
    float fb = (kb < split) ? srcA[(size_t)kb * H5 + col] : srcB[(size_t)(kb - split) * H5 + col];
    w[p] = f2bf(fa) | (f2bf(fb) << 16);
  }
  u32x4 v; unsigned int* vp = (unsigned int*)&v;
  vp[0] = w[0]; vp[1] = w[1]; vp[2] = w[2]; vp[3] = w[3];
  *((u32x4*)(dst + (size_t)t * 8)) = v;
}

// f32 -> bf16 row-major cast, 8 elements/thread.
__global__ void cast_leaf(const float* __restrict__ src,
                          unsigned short* __restrict__ dst, long n8) {
  long t = (long)blockIdx.x * blockDim.x + threadIdx.x;
  if (t >= n8) return;
  const float4* s = (const float4*)src + t * 2;
  float4 x = s[0], y = s[1];
  u32x4 v; unsigned int* vp = (unsigned int*)&v;
  vp[0] = f2bf(x.x) | (f2bf(x.y) << 16);
  vp[1] = f2bf(x.z) | (f2bf(x.w) << 16);
  vp[2] = f2bf(y.x) | (f2bf(y.y) << 16);
  vp[3] = f2bf(y.z) | (f2bf(y.w) << 16);
  *((u32x4*)(dst + t * 8)) = v;
}

// ---------------------------------------------------------------------------
// Fused level kernel. A: [n][K] bf16 row-major. 8 waves/block; blockIdx.y
// selects 16 h-cols; B panel staged in LDS once; grid-stride row tiles.
template <int KT, bool HAS_C>
__global__ __launch_bounds__(512, 4) void level_fused(
    const unsigned short* __restrict__ A,
    const unsigned short* __restrict__ Bpk,
    const float* __restrict__ bx,
    const float* __restrict__ c_child,
    unsigned short* __restrict__ h_out,
    float* __restrict__ c_out,
    float* __restrict__ h_f32_out,
    int n, int NT) {
  constexpr int K = KT * 32;
  __shared__ unsigned short smemB[5 * KT * 512];
  const int lane = threadIdx.x & 63;
  const int wid = threadIdx.x >> 6;
  const int by = blockIdx.y;

  for (int e = wid; e < 5 * KT; e += 8) {
    int g = e / KT, kt = e % KT;
    const u32x4* src =
        (const u32x4*)(Bpk + ((size_t)((g * 8 + by) * KT + kt) * 512) + lane * 8);
    *((u32x4*)(smemB + e * 512 + lane * 8)) = *src;
  }
  __syncthreads();

  const int jc = by * 16 + (lane & 15);
  float bxv[5];
#pragma unroll
  for (int g = 0; g < 5; ++g) bxv[g] = bx[g * 128 + jc];

  const int kch = (lane >> 4) * 8;

  for (int t = blockIdx.x; t < NT; t += gridDim.x) {
    const int r0 = t * 256 + wid * 32 + (lane & 15);
    f32x4 acc[2][5];
#pragma unroll
    for (int m = 0; m < 2; ++m)
#pragma unroll
      for (int g = 0; g < 5; ++g) acc[m][g] = (f32x4)0.0f;

#pragma unroll 2
    for (int kt = 0; kt < KT; ++kt) {
      bf16x8 a[2];
#pragma unroll
      for (int m = 0; m < 2; ++m)
        a[m] = *(const bf16x8*)(A + (size_t)(r0 + m * 16) * K + kt * 32 + kch);
#pragma unroll
      for (int g = 0; g < 5; ++g) {
        bf16x8 b = *(const bf16x8*)(smemB + (g * KT + kt) * 512 + lane * 8);
        acc[0][g] = __builtin_amdgcn_mfma_f32_16x16x32_bf16(a[0], b, acc[0][g], 0, 0, 0);
        acc[1][g] = __builtin_amdgcn_mfma_f32_16x16x32_bf16(a[1], b, acc[1][g], 0, 0, 0);
      }
    }

#pragma unroll
    for (int m = 0; m < 2; ++m) {
      const int ib = t * 256 + wid * 32 + m * 16 + (lane >> 4) * 4;
#pragma unroll
      for (int reg = 0; reg < 4; ++reg) {
        const int i = ib + reg;
        if (i >= n) continue;
        float gi = acc[m][0][reg] + bxv[0];
        float go = acc[m][3][reg] + bxv[3];
        float gu = acc[m][4][reg] + bxv[4];
        float c = sigf(gi) * tanh_fast(gu);
        if (HAS_C) {
          float gfL = acc[m][1][reg] + bxv[1];
          float gfR = acc[m][2][reg] + bxv[2];
          float cL = c_child[(size_t)(2 * i) * HH + jc];
          float cR = c_child[(size_t)(2 * i + 1) * HH + jc];
          c += sigf(gfL) * cL + sigf(gfR) * cR;
        }
        float h = sigf(go) * tanh_fast(c);
        h_out[(size_t)i * HH + jc] = (unsigned short)f2bf(h);
        c_out[(size_t)i * HH + jc] = c;
        if (h_f32_out) h_f32_out[(size_t)i * HH + jc] = h;
      }
    }
  }
}

// ---------------------------------------------------------------------------
// Tail: 10 levels (input n=1024 -> output 1) fused in one launch.
// Grid 8x8 = 64 blocks; weights stay in LDS; device-scope barrier per level.
// Each level writes a FRESH slab (no address reuse -> no stale cross-XCD
// cachelines); A-row reads clamped in-bounds.
__global__ __launch_bounds__(512, 4) void tail_fused(
    const unsigned short* __restrict__ h_in0,
    const float* __restrict__ c_in0,
    const unsigned short* __restrict__ Bpk,
    const float* __restrict__ bx,
    unsigned short* __restrict__ tailH,
    float* __restrict__ tailC,
    float* __restrict__ out,
    int* __restrict__ bar) {
  constexpr int KT = 8;
  constexpr int K = 256;
  __shared__ unsigned short smemB[5 * KT * 512];
  const int lane = threadIdx.x & 63;
  const int wid = threadIdx.x >> 6;
  const int by = blockIdx.y;
  const int bxk = blockIdx.x;

  for (int e = wid; e < 5 * KT; e += 8) {
    int g = e / KT, kt = e % KT;
    const u32x4* src =
        (const u32x4*)(Bpk + ((size_t)((g * 8 + by) * KT + kt) * 512) + lane * 8);
    *((u32x4*)(smemB + e * 512 + lane * 8)) = *src;
  }
  __syncthreads();

  const int jc = by * 16 + (lane & 15);
  float bxv[5];
#pragma unroll
  for (int g = 0; g < 5; ++g) bxv[g] = bx[g * 128 + jc];
  const int kch = (lane >> 4) * 8;

  const unsigned short* hin = h_in0;
  const float* cin = c_in0;
  size_t off = 0;
  int nout = 512;
  for (int l = 0; l < 10; ++l, nout >>= 1) {
    unsigned short* hout = tailH + off * HH;
    float* cout = tailC + off * HH;
    const int NT = (nout + 255) >> 8;
    for (int t = bxk; t < NT; t += 8) {
      const int r0 = t * 256 + wid * 32 + (lane & 15);
      f32x4 acc[2][5];
#pragma unroll
      for (int m = 0; m < 2; ++m)
#pragma unroll
        for (int g = 0; g < 5; ++g) acc[m][g] = (f32x4)0.0f;

      for (int kt = 0; kt < KT; ++kt) {
        bf16x8 a[2];
#pragma unroll
        for (int m = 0; m < 2; ++m) {
          int ar = r0 + m * 16;
          if (ar >= nout) ar = 0;  // clamp: no OOB slab reads (coherence!)
          a[m] = *(const bf16x8*)(hin + (size_t)ar * K + kt * 32 + kch);
        }
#pragma unroll
        for (int g = 0; g < 5; ++g) {
          bf16x8 b = *(const bf16x8*)(smemB + (g * KT + kt) * 512 + lane * 8);
          acc[0][g] = __builtin_amdgcn_mfma_f32_16x16x32_bf16(a[0], b, acc[0][g], 0, 0, 0);
          acc[1][g] = __builtin_amdgcn_mfma_f32_16x16x32_bf16(a[1], b, acc[1][g], 0, 0, 0);
        }
      }

#pragma unroll
      for (int m = 0; m < 2; ++m) {
        const int ib = t * 256 + wid * 32 + m * 16 + (lane >> 4) * 4;
#pragma unroll
        for (int reg = 0; reg < 4; ++reg) {
          const int i = ib + reg;
          if (i >= nout) continue;
          float gi = acc[m][0][reg] + bxv[0];
          float go = acc[m][3][reg] + bxv[3];
          float gu = acc[m][4][reg] + bxv[4];
          float gfL = acc[m][1][reg] + bxv[1];
          float gfR = acc[m][2][reg] + bxv[2];
          float c = sigf(gi) * tanh_fast(gu) +
                    sigf(gfL) * cin[(size_t)(2 * i) * HH + jc] +
                    sigf(gfR) * cin[(size_t)(2 * i + 1) * HH + jc];
          float h = sigf(go) * tanh_fast(c);
          hout[(size_t)i * HH + jc] = (unsigned short)f2bf(h);
          cout[(size_t)i * HH + jc] = c;
          if (l == 9) out[jc] = h;  // only i==0 reaches here at l==9
        }
      }
    }

    if (l < 9) {  // device-scope barrier between levels
      __syncthreads();
      if (threadIdx.x == 0) {
        __threadfence();
        atomicAdd(&bar[l], 1);
        while (__hip_atomic_load(&bar[l], __ATOMIC_ACQUIRE,
                                 __HIP_MEMORY_SCOPE_AGENT) < 64) {
          __builtin_amdgcn_s_sleep(1);
        }
      }
      __syncthreads();
    }
    hin = hout;
    cin = cout;
    off += nout;
  }
}

// ---------------------------------------------------------------------------
extern "C" void kernel_launch(void* const* d_in, const int* in_sizes, int n_in,
                              void* d_out, int out_size, void* d_ws, size_t ws_size,
                              hipStream_t stream) {
  const float* leaf = (const float*)d_in[0];
  const float* Wx = (const float*)d_in[1];
  const float* bx = (const float*)d_in[2];
  const float* UL = (const float*)d_in[3];
  const float* UR = (const float*)d_in[4];
  float* out = (float*)d_out;

  char* ws = (char*)d_ws;
  size_t off = 0;
  auto alloc = [&](size_t bytes) -> void* {
    void* p = ws + off;
    off += (bytes + 1023) & ~(size_t)1023;
    return p;
  };
  unsigned short* Wx_pk = (unsigned short*)alloc((size_t)40 * 4 * 64 * 8 * 2);
  unsigned short* U_pk = (unsigned short*)alloc((size_t)40 * 8 * 64 * 8 * 2);
  unsigned short* leaf_bf = (unsigned short*)alloc((size_t)NLEAF * HH * 2);
  unsigned short* hA = (unsigned short*)alloc((size_t)NLEAF * HH * 2);
  unsigned short* hB = (unsigned short*)alloc((size_t)(NLEAF / 2) * HH * 2);
  float* cA = (float*)alloc((size_t)NLEAF * HH * 4);
  float* cB = (float*)alloc((size_t)(NLEAF / 2) * HH * 4);
  unsigned short* tailH = (unsigned short*)alloc((size_t)2048 * HH * 2);
  float* tailC = (float*)alloc((size_t)2048 * HH * 4);
  int* bar = (int*)alloc(64 * sizeof(int));

  pack_weights<<<(40 * 4 * 64 + 255) / 256, 256, 0, stream>>>(Wx, Wx, 128, 4, Wx_pk);
  pack_weights<<<(40 * 8 * 64 + 255) / 256, 256, 0, stream>>>(UL, UR, 128, 8, U_pk);
  long n8 = (long)NLEAF * HH / 8;
  cast_leaf<<<(unsigned)(n8 / 256), 256, 0, stream>>>(leaf, leaf_bf, n8);

  // Leaf: [262144,128] bf16 @ Wx[128,640].
  level_fused<4, false><<<dim3(128, 8), 512, 0, stream>>>(
      leaf_bf, Wx_pk, bx, nullptr, hA, cA, nullptr, NLEAF, NLEAF / 256);

  // Big internal levels: outputs 131072 .. 1024.
  unsigned short* hs[2] = {hA, hB};
  float* cs[2] = {cA, cB};
  int cur = 0;
  int n = NLEAF / 2;
  for (int lvl = 1; lvl <= 8; ++lvl) {
    int NT = (n + 255) / 256;
    int gx = NT < 128 ? NT : 128;
    level_fused<8, true><<<dim3(gx, 8), 512, 0, stream>>>(
        hs[cur], U_pk, bx, cs[cur], hs[cur ^ 1], cs[cur ^ 1], nullptr, n, NT);
    cur ^= 1;
    n >>= 1;
  }

  // Tail: input 1024 rows (hs[cur]) -> 10 fused levels -> out.
  hipMemsetAsync(bar, 0, 64 * sizeof(int), stream);
  tail_fused<<<dim3(8, 8), 512, 0, stream>>>(
      hs[cur], cs[cur], U_pk, bx, tailH, tailC, out, bar);

  (void)in_sizes; (void)n_in; (void)out_size; (void)ws_size;
}

// Round 10
// 787.174 us; speedup vs baseline: 1.0496x; 1.0496x over previous
//
#include <hip/hip_runtime.h>
#include <hip/hip_bf16.h>
#include <stdint.h>

// TreeLSTM on MI355X. H=D=128, 5H=640, N_LEAVES=2^18, 18 internal levels.
// v4: per-level launches (tail_fused grid-barrier reverted: 232us of spin),
// MR=4 per wave (64 rows) with 256-thread blocks -> 20 MFMA per 5 ds_reads.

#define H5 640
#define HH 128
#define NLEAF 262144

typedef __attribute__((ext_vector_type(4))) float f32x4;
typedef __attribute__((ext_vector_type(8))) short bf16x8;
typedef __attribute__((ext_vector_type(4))) unsigned int u32x4;

static __device__ __forceinline__ unsigned int f2bf(float f) {
  union { float f; unsigned int i; } v; v.f = f;
  unsigned int r = v.i + 0x7FFF + ((v.i >> 16) & 1);  // RNE
  return r >> 16;
}

static __device__ __forceinline__ float sigf(float x) {
  return 1.0f / (1.0f + __expf(-x));
}
static __device__ __forceinline__ float tanh_fast(float x) {
  float t = __expf(2.0f * x);
  return (t - 1.0f) / (t + 1.0f);
}

// ---------------------------------------------------------------------------
// Pack a [K,640] f32 weight (rows k<split from srcA, else srcB) into MFMA
// B-fragment layout: frag (nf,kf): lane l holds B[kf*32+(l>>4)*8+e][nf*16+(l&15)],
// e=0..7. Element offset = ((nf*KT + kf)*64 + lane)*8.  (validated r1/r4/r9)
__global__ void pack_weights(const float* __restrict__ srcA,
                             const float* __restrict__ srcB,
                             int split, int KT, unsigned short* __restrict__ dst) {
  int t = blockIdx.x * blockDim.x + threadIdx.x;
  int total = 40 * KT * 64;
  if (t >= total) return;
  int lane = t & 63;
  int kf = (t >> 6) % KT;
  int nf = (t >> 6) / KT;
  int col = nf * 16 + (lane & 15);
  int k0 = kf * 32 + (lane >> 4) * 8;
  unsigned int w[4];
#pragma unroll
  for (int p = 0; p < 4; ++p) {
    int ka = k0 + 2 * p, kb = k0 + 2 * p + 1;
    float fa = (ka < split) ? srcA[(size_t)ka * H5 + col] : srcB[(size_t)(ka - split) * H5 + col];
    float fb = (kb < split) ? srcA[(size_t)kb * H5 + col] : srcB[(size_t)(kb - split) * H5 + col];
    w[p] = f2bf(fa) | (f2bf(fb) << 16);
  }
  u32x4 v; unsigned int* vp = (unsigned int*)&v;
  vp[0] = w[0]; vp[1] = w[1]; vp[2] = w[2]; vp[3] = w[3];
  *((u32x4*)(dst + (size_t)t * 8)) = v;
}

// f32 -> bf16 row-major cast, 8 elements/thread.
__global__ void cast_leaf(const float* __restrict__ src,
                          unsigned short* __restrict__ dst, long n8) {
  long t = (long)blockIdx.x * blockDim.x + threadIdx.x;
  if (t >= n8) return;
  const float4* s = (const float4*)src + t * 2;
  float4 x = s[0], y = s[1];
  u32x4 v; unsigned int* vp = (unsigned int*)&v;
  vp[0] = f2bf(x.x) | (f2bf(x.y) << 16);
  vp[1] = f2bf(x.z) | (f2bf(x.w) << 16);
  vp[2] = f2bf(y.x) | (f2bf(y.y) << 16);
  vp[3] = f2bf(y.z) | (f2bf(y.w) << 16);
  *((u32x4*)(dst + t * 8)) = v;
}

// ---------------------------------------------------------------------------
// Fused level kernel. A: [n][K] bf16 row-major. 4 waves/block; each wave owns
// 64 rows (4 M-frags); blockIdx.y selects 16 h-cols; B panel in LDS (staged
// once); grid-stride over 256-row tiles. 5 ds_reads feed 20 MFMAs per K-step.
template <int KT, bool HAS_C>
__global__ __launch_bounds__(256, 4) void level_fused(
    const unsigned short* __restrict__ A,
    const unsigned short* __restrict__ Bpk,
    const float* __restrict__ bx,
    const float* __restrict__ c_child,
    unsigned short* __restrict__ h_out,
    float* __restrict__ c_out,
    float* __restrict__ h_f32_out,
    int n, int NT) {
  constexpr int K = KT * 32;
  __shared__ unsigned short smemB[5 * KT * 512];  // 20KB leaf / 40KB internal
  const int lane = threadIdx.x & 63;
  const int wid = threadIdx.x >> 6;  // 0..3
  const int by = blockIdx.y;

  for (int e = wid; e < 5 * KT; e += 4) {
    int g = e / KT, kt = e % KT;
    const u32x4* src =
        (const u32x4*)(Bpk + ((size_t)((g * 8 + by) * KT + kt) * 512) + lane * 8);
    *((u32x4*)(smemB + e * 512 + lane * 8)) = *src;
  }
  __syncthreads();

  const int jc = by * 16 + (lane & 15);
  float bxv[5];
#pragma unroll
  for (int g = 0; g < 5; ++g) bxv[g] = bx[g * 128 + jc];

  const int kch = (lane >> 4) * 8;

  for (int t = blockIdx.x; t < NT; t += gridDim.x) {
    const int r0 = t * 256 + wid * 64 + (lane & 15);
    f32x4 acc[4][5];
#pragma unroll
    for (int m = 0; m < 4; ++m)
#pragma unroll
      for (int g = 0; g < 5; ++g) acc[m][g] = (f32x4)0.0f;

#pragma unroll 2
    for (int kt = 0; kt < KT; ++kt) {
      bf16x8 a[4];
#pragma unroll
      for (int m = 0; m < 4; ++m)
        a[m] = *(const bf16x8*)(A + (size_t)(r0 + m * 16) * K + kt * 32 + kch);
#pragma unroll
      for (int g = 0; g < 5; ++g) {
        bf16x8 b = *(const bf16x8*)(smemB + (g * KT + kt) * 512 + lane * 8);
#pragma unroll
        for (int m = 0; m < 4; ++m)
          acc[m][g] = __builtin_amdgcn_mfma_f32_16x16x32_bf16(a[m], b, acc[m][g], 0, 0, 0);
      }
    }

    // Epilogue. C/D frag: col = lane&15 (=jc), row = (lane>>4)*4 + reg.
#pragma unroll
    for (int m = 0; m < 4; ++m) {
      const int ib = t * 256 + wid * 64 + m * 16 + (lane >> 4) * 4;
#pragma unroll
      for (int reg = 0; reg < 4; ++reg) {
        const int i = ib + reg;
        if (i >= n) continue;
        float gi = acc[m][0][reg] + bxv[0];
        float go = acc[m][3][reg] + bxv[3];
        float gu = acc[m][4][reg] + bxv[4];
        float c = sigf(gi) * tanh_fast(gu);
        if (HAS_C) {
          float gfL = acc[m][1][reg] + bxv[1];
          float gfR = acc[m][2][reg] + bxv[2];
          float cL = c_child[(size_t)(2 * i) * HH + jc];
          float cR = c_child[(size_t)(2 * i + 1) * HH + jc];
          c += sigf(gfL) * cL + sigf(gfR) * cR;
        }
        float h = sigf(go) * tanh_fast(c);
        h_out[(size_t)i * HH + jc] = (unsigned short)f2bf(h);
        c_out[(size_t)i * HH + jc] = c;
        if (h_f32_out) h_f32_out[(size_t)i * HH + jc] = h;
      }
    }
  }
}

// ---------------------------------------------------------------------------
extern "C" void kernel_launch(void* const* d_in, const int* in_sizes, int n_in,
                              void* d_out, int out_size, void* d_ws, size_t ws_size,
                              hipStream_t stream) {
  const float* leaf = (const float*)d_in[0];
  const float* Wx = (const float*)d_in[1];
  const float* bx = (const float*)d_in[2];
  const float* UL = (const float*)d_in[3];
  const float* UR = (const float*)d_in[4];
  float* out = (float*)d_out;

  char* ws = (char*)d_ws;
  size_t off = 0;
  auto alloc = [&](size_t bytes) -> void* {
    void* p = ws + off;
    off += (bytes + 1023) & ~(size_t)1023;
    return p;
  };
  unsigned short* Wx_pk = (unsigned short*)alloc((size_t)40 * 4 * 64 * 8 * 2);
  unsigned short* U_pk = (unsigned short*)alloc((size_t)40 * 8 * 64 * 8 * 2);
  unsigned short* leaf_bf = (unsigned short*)alloc((size_t)NLEAF * HH * 2);
  unsigned short* hA = (unsigned short*)alloc((size_t)NLEAF * HH * 2);
  unsigned short* hB = (unsigned short*)alloc((size_t)(NLEAF / 2) * HH * 2);
  float* cA = (float*)alloc((size_t)NLEAF * HH * 4);
  float* cB = (float*)alloc((size_t)(NLEAF / 2) * HH * 4);

  pack_weights<<<(40 * 4 * 64 + 255) / 256, 256, 0, stream>>>(Wx, Wx, 128, 4, Wx_pk);
  pack_weights<<<(40 * 8 * 64 + 255) / 256, 256, 0, stream>>>(UL, UR, 128, 8, U_pk);
  long n8 = (long)NLEAF * HH / 8;
  cast_leaf<<<(unsigned)(n8 / 256), 256, 0, stream>>>(leaf, leaf_bf, n8);

  // Leaf: [262144,128] bf16 @ Wx[128,640]. NT=1024 tiles of 256 rows.
  level_fused<4, false><<<dim3(128, 8), 256, 0, stream>>>(
      leaf_bf, Wx_pk, bx, nullptr, hA, cA, nullptr, NLEAF, NLEAF / 256);

  // Internal levels: outputs 131072 .. 1.
  unsigned short* hs[2] = {hA, hB};
  float* cs[2] = {cA, cB};
  int cur = 0;
  int n = NLEAF / 2;
  for (int lvl = 1; lvl <= 18; ++lvl) {
    float* f32out = (lvl == 18) ? out : nullptr;
    int NT = (n + 255) / 256;
    int gx = NT < 128 ? NT : 128;
    level_fused<8, true><<<dim3(gx, 8), 256, 0, stream>>>(
        hs[cur], U_pk, bx, cs[cur], hs[cur ^ 1], cs[cur ^ 1], f32out, n, NT);
    cur ^= 1;
    n >>= 1;
  }
  (void)in_sizes; (void)n_in; (void)out_size; (void)ws_size;
}

// Round 14
// 786.081 us; speedup vs baseline: 1.0511x; 1.0014x over previous
//
#include <hip/hip_runtime.h>
#include <hip/hip_bf16.h>
#include <stdint.h>

// TreeLSTM on MI355X. H=D=128, 5H=640, N_LEAVES=2^18, 18 internal levels.
// v5: c stored COLUMN-MAJOR [128][ld(n)] (ld = max(n,4)) -> epilogue c access
// becomes dwordx4 (cL=even, cR=odd lanes of an 8-float run) instead of 8
// scalar loads + 4 scalar stores per m-frag. h stays row-major (GEMM A).
// MR=4 per wave (64 rows), 256-thr blocks, per-level launches.

#define H5 640
#define HH 128
#define NLEAF 262144

typedef __attribute__((ext_vector_type(4))) float f32x4;
typedef __attribute__((ext_vector_type(8))) short bf16x8;
typedef __attribute__((ext_vector_type(4))) unsigned int u32x4;

static __device__ __forceinline__ unsigned int f2bf(float f) {
  union { float f; unsigned int i; } v; v.f = f;
  unsigned int r = v.i + 0x7FFF + ((v.i >> 16) & 1);  // RNE
  return r >> 16;
}

static __device__ __forceinline__ float sigf(float x) {
  return 1.0f / (1.0f + __expf(-x));
}
static __device__ __forceinline__ float tanh_fast(float x) {
  float t = __expf(2.0f * x);
  return (t - 1.0f) / (t + 1.0f);
}

// ---------------------------------------------------------------------------
// Pack a [K,640] f32 weight (rows k<split from srcA, else srcB) into MFMA
// B-fragment layout: frag (nf,kf): lane l holds B[kf*32+(l>>4)*8+e][nf*16+(l&15)],
// e=0..7. Element offset = ((nf*KT + kf)*64 + lane)*8.  (validated r1/r4/r10)
__global__ void pack_weights(const float* __restrict__ srcA,
                             const float* __restrict__ srcB,
                             int split, int KT, unsigned short* __restrict__ dst) {
  int t = blockIdx.x * blockDim.x + threadIdx.x;
  int total = 40 * KT * 64;
  if (t >= total) return;
  int lane = t & 63;
  int kf = (t >> 6) % KT;
  int nf = (t >> 6) / KT;
  int col = nf * 16 + (lane & 15);
  int k0 = kf * 32 + (lane >> 4) * 8;
  unsigned int w[4];
#pragma unroll
  for (int p = 0; p < 4; ++p) {
    int ka = k0 + 2 * p, kb = k0 + 2 * p + 1;
    float fa = (ka < split) ? srcA[(size_t)ka * H5 + col] : srcB[(size_t)(ka - split) * H5 + col];
    float fb = (kb < split) ? srcA[(size_t)kb * H5 + col] : srcB[(size_t)(kb - split) * H5 + col];
    w[p] = f2bf(fa) | (f2bf(fb) << 16);
  }
  u32x4 v; unsigned int* vp = (unsigned int*)&v;
  vp[0] = w[0]; vp[1] = w[1]; vp[2] = w[2]; vp[3] = w[3];
  *((u32x4*)(dst + (size_t)t * 8)) = v;
}

// f32 -> bf16 row-major cast, 8 elements/thread.
__global__ void cast_leaf(const float* __restrict__ src,
                          unsigned short* __restrict__ dst, long n8) {
  long t = (long)blockIdx.x * blockDim.x + threadIdx.x;
  if (t >= n8) return;
  const float4* s = (const float4*)src + t * 2;
  float4 x = s[0], y = s[1];
  u32x4 v; unsigned int* vp = (unsigned int*)&v;
  vp[0] = f2bf(x.x) | (f2bf(x.y) << 16);
  vp[1] = f2bf(x.z) | (f2bf(x.w) << 16);
  vp[2] = f2bf(y.x) | (f2bf(y.y) << 16);
  vp[3] = f2bf(y.z) | (f2bf(y.w) << 16);
  *((u32x4*)(dst + t * 8)) = v;
}

// ---------------------------------------------------------------------------
// Fused level kernel. A: [n][K] bf16 row-major. c: col-major [128][ld].
// 4 waves/block; wave owns 64 rows (4 M-frags); blockIdx.y = 16 h-cols;
// B panel in LDS; grid-stride over 256-row tiles.
template <int KT, bool HAS_C, bool WRITE_F32>
__global__ __launch_bounds__(256, 4) void level_fused(
    const unsigned short* __restrict__ A,
    const unsigned short* __restrict__ Bpk,
    const float* __restrict__ bx,
    const float* __restrict__ c_child,   // col-major, leading dim ldr
    unsigned short* __restrict__ h_out,  // row-major [n][128]
    float* __restrict__ c_out,           // col-major, leading dim ldw
    float* __restrict__ h_f32_out,
    int n, int NT, int ldr, int ldw) {
  constexpr int K = KT * 32;
  __shared__ unsigned short smemB[5 * KT * 512];  // 20KB leaf / 40KB internal
  const int lane = threadIdx.x & 63;
  const int wid = threadIdx.x >> 6;  // 0..3
  const int by = blockIdx.y;

  for (int e = wid; e < 5 * KT; e += 4) {
    int g = e / KT, kt = e % KT;
    const u32x4* src =
        (const u32x4*)(Bpk + ((size_t)((g * 8 + by) * KT + kt) * 512) + lane * 8);
    *((u32x4*)(smemB + e * 512 + lane * 8)) = *src;
  }
  __syncthreads();

  const int jc = by * 16 + (lane & 15);
  float bxv[5];
#pragma unroll
  for (int g = 0; g < 5; ++g) bxv[g] = bx[g * 128 + jc];

  const int kch = (lane >> 4) * 8;

  for (int t = blockIdx.x; t < NT; t += gridDim.x) {
    const int r0 = t * 256 + wid * 64 + (lane & 15);
    f32x4 acc[4][5];
#pragma unroll
    for (int m = 0; m < 4; ++m)
#pragma unroll
      for (int g = 0; g < 5; ++g) acc[m][g] = (f32x4)0.0f;

#pragma unroll 2
    for (int kt = 0; kt < KT; ++kt) {
      bf16x8 a[4];
#pragma unroll
      for (int m = 0; m < 4; ++m)
        a[m] = *(const bf16x8*)(A + (size_t)(r0 + m * 16) * K + kt * 32 + kch);
#pragma unroll
      for (int g = 0; g < 5; ++g) {
        bf16x8 b = *(const bf16x8*)(smemB + (g * KT + kt) * 512 + lane * 8);
#pragma unroll
        for (int m = 0; m < 4; ++m)
          acc[m][g] = __builtin_amdgcn_mfma_f32_16x16x32_bf16(a[m], b, acc[m][g], 0, 0, 0);
      }
    }

    // --- Epilogue. C/D frag: col = lane&15 (=jc), row = (lane>>4)*4 + reg.
    const int ib0 = t * 256 + wid * 64 + (lane >> 4) * 4;
    f32x4 cva[4], cvb[4];
    if (HAS_C) {
#pragma unroll
      for (int m = 0; m < 4; ++m) {
        const float* p = c_child + (size_t)jc * ldr + 2 * (ib0 + m * 16);
        cva[m] = *(const f32x4*)p;
        cvb[m] = *(const f32x4*)(p + 4);
      }
    }
#pragma unroll
    for (int m = 0; m < 4; ++m) {
      const int ibm = ib0 + m * 16;
      f32x4 cst;
#pragma unroll
      for (int reg = 0; reg < 4; ++reg) {
        const int i = ibm + reg;
        float gi = acc[m][0][reg] + bxv[0];
        float go = acc[m][3][reg] + bxv[3];
        float gu = acc[m][4][reg] + bxv[4];
        float c = sigf(gi) * tanh_fast(gu);
        if (HAS_C) {
          float gfL = acc[m][1][reg] + bxv[1];
          float gfR = acc[m][2][reg] + bxv[2];
          float cL = (reg < 2) ? cva[m][2 * reg] : cvb[m][2 * (reg - 2)];
          float cR = (reg < 2) ? cva[m][2 * reg + 1] : cvb[m][2 * (reg - 2) + 1];
          c += sigf(gfL) * cL + sigf(gfR) * cR;
        }
        cst[reg] = c;
        if (i < n) {
          float h = sigf(go) * tanh_fast(c);
          h_out[(size_t)i * HH + jc] = (unsigned short)f2bf(h);
          if (WRITE_F32) h_f32_out[(size_t)i * HH + jc] = h;
        }
      }
      if (ibm < n)  // padded column (ldw>=4, mult of 4) absorbs the tail
        *((f32x4*)(c_out + (size_t)jc * ldw + ibm)) = cst;
    }
  }
}

// ---------------------------------------------------------------------------
extern "C" void kernel_launch(void* const* d_in, const int* in_sizes, int n_in,
                              void* d_out, int out_size, void* d_ws, size_t ws_size,
                              hipStream_t stream) {
  const float* leaf = (const float*)d_in[0];
  const float* Wx = (const float*)d_in[1];
  const float* bx = (const float*)d_in[2];
  const float* UL = (const float*)d_in[3];
  const float* UR = (const float*)d_in[4];
  float* out = (float*)d_out;

  char* ws = (char*)d_ws;
  size_t off = 0;
  auto alloc = [&](size_t bytes) -> void* {
    void* p = ws + off;
    off += (bytes + 1023) & ~(size_t)1023;
    return p;
  };
  auto ldof = [](int n) { return n < 4 ? 4 : n; };

  unsigned short* Wx_pk = (unsigned short*)alloc((size_t)40 * 4 * 64 * 8 * 2);
  unsigned short* U_pk = (unsigned short*)alloc((size_t)40 * 8 * 64 * 8 * 2);
  unsigned short* leaf_bf = (unsigned short*)alloc((size_t)NLEAF * HH * 2);
  unsigned short* hA = (unsigned short*)alloc((size_t)NLEAF * HH * 2);
  unsigned short* hB = (unsigned short*)alloc((size_t)(NLEAF / 2) * HH * 2);
  float* cA = (float*)alloc((size_t)NLEAF * HH * 4);        // col-major slabs
  float* cB = (float*)alloc((size_t)(NLEAF / 2) * HH * 4);

  pack_weights<<<(40 * 4 * 64 + 255) / 256, 256, 0, stream>>>(Wx, Wx, 128, 4, Wx_pk);
  pack_weights<<<(40 * 8 * 64 + 255) / 256, 256, 0, stream>>>(UL, UR, 128, 8, U_pk);
  long n8 = (long)NLEAF * HH / 8;
  cast_leaf<<<(unsigned)(n8 / 256), 256, 0, stream>>>(leaf, leaf_bf, n8);

  // Leaf: [262144,128] bf16 @ Wx[128,640]; c written col-major ld=NLEAF.
  level_fused<4, false, false><<<dim3(128, 8), 256, 0, stream>>>(
      leaf_bf, Wx_pk, bx, nullptr, hA, cA, nullptr, NLEAF, NLEAF / 256, 0, NLEAF);

  // Internal levels: outputs 131072 .. 1.
  unsigned short* hs[2] = {hA, hB};
  float* cs[2] = {cA, cB};
  int cur = 0;
  int n = NLEAF / 2;
  for (int lvl = 1; lvl <= 18; ++lvl) {
    int NT = (n + 255) / 256;
    int gx = NT < 128 ? NT : 128;
    int ldr = ldof(2 * n), ldw = ldof(n);
    if (lvl < 18) {
      level_fused<8, true, false><<<dim3(gx, 8), 256, 0, stream>>>(
          hs[cur], U_pk, bx, cs[cur], hs[cur ^ 1], cs[cur ^ 1], nullptr,
          n, NT, ldr, ldw);
    } else {
      level_fused<8, true, true><<<dim3(gx, 8), 256, 0, stream>>>(
          hs[cur], U_pk, bx, cs[cur], hs[cur ^ 1], cs[cur ^ 1], out,
          n, NT, ldr, ldw);
    }
    cur ^= 1;
    n >>= 1;
  }
  (void)in_sizes; (void)n_in; (void)out_size; (void)ws_size;
}